// Round 1
// baseline (2616.734 us; speedup 1.0000x reference)
//
#include <hip/hip_runtime.h>
#include <hip/hip_bf16.h>
#include <stdint.h>

#define B_ 256
#define S_ 64
#define D_ 256
#define H_ 1024
#define O_ 512
#define G_ 3072          // 3*H
#define BH_ (B_ * H_)    // 262144

typedef unsigned short u16;
typedef __attribute__((ext_vector_type(8))) short bf16x8;
typedef __attribute__((ext_vector_type(4))) float f32x4;

#define MFMA16(a, b, c) __builtin_amdgcn_mfma_f32_16x16x32_bf16((a), (b), (c), 0, 0, 0)

__device__ __forceinline__ u16 f2b(float f) {
    union { float f; uint32_t u; } v; v.f = f;
    uint32_t u = v.u;
    uint32_t r = (u + 0x7fffu + ((u >> 16) & 1u)) >> 16;   // RNE
    return (u16)r;
}
__device__ __forceinline__ float b2f(u16 b) {
    union { uint32_t u; float f; } v; v.u = ((uint32_t)b) << 16;
    return v.f;
}

__device__ __forceinline__ void gl_lds16(const u16* g, u16* l) {
    __builtin_amdgcn_global_load_lds(
        (const __attribute__((address_space(1))) unsigned int*)g,
        (__attribute__((address_space(3))) unsigned int*)l, 16, 0, 0);
}

// ---------------- prep kernels ----------------

__global__ void k_conv(const float* __restrict__ s, u16* __restrict__ d, int n) {
    int i = blockIdx.x * blockDim.x + threadIdx.x;
    int st = gridDim.x * blockDim.x;
    for (; i < n; i += st) d[i] = f2b(s[i]);
}

// lin_w [S][H][O] f32 -> [S][O][H] bf16
__global__ __launch_bounds__(256) void k_twl(const float* __restrict__ w, u16* __restrict__ o) {
    __shared__ float tile[32][33];
    int bid = blockIdx.x;
    int t = bid >> 9;            // 512 tiles / t  (32 j-tiles x 16 o-tiles)
    int rem = bid & 511;
    int j0 = (rem >> 4) << 5;
    int o0 = (rem & 15) << 5;
    int tx = threadIdx.x & 31, ty = threadIdx.x >> 5;
    const float* base = w + (size_t)t * (H_ * O_);
#pragma unroll
    for (int i = 0; i < 4; ++i) {
        int r = ty + (i << 3);
        tile[r][tx] = base[(size_t)(j0 + r) * O_ + o0 + tx];
    }
    __syncthreads();
    u16* ob = o + (size_t)t * (O_ * H_);
#pragma unroll
    for (int i = 0; i < 4; ++i) {
        int r = ty + (i << 3);
        ob[(size_t)(o0 + r) * H_ + j0 + tx] = f2b(tile[tx][r]);
    }
}

// ---------------- GRU wavefront phase ----------------

struct PhaseArgs {
    const u16* Xb;
    const u16 *Wi0, *Wh0, *Wi1, *Wh1, *Wi2, *Wh2;
    const float *bi0, *bh0, *bi1, *bh1, *bi2, *bh2;
    u16 *h0b, *h1b, *h2all;      // bf16 state (h2all: 65 slots, slot t+1 = time t)
    float *h0f, *h1f, *h2f;      // fp32 state (double-buffered)
};

__global__ __launch_bounds__(256) void k_phase(PhaseArgs p, int k) {
    int cell = blockIdx.x >> 6;          // 64 tiles per cell
    int t = k - cell;
    if (t < 0 || t >= S_) return;
    int tile = blockIdx.x & 63;
    int b0 = (tile >> 4) << 6;           // 4 b-tiles of 64
    int j0 = (tile & 15) << 6;           // 16 j-tiles of 64

    const u16 *A0, *A1, *Wi, *Wh;
    const float *bi, *bh, *A1f;
    u16* hout;
    float* houtf;
    int ld0, K0;
    if (cell == 0) {
        A0 = p.Xb + t * D_; ld0 = S_ * D_; K0 = D_;
        A1 = p.h0b + ((t + 1) & 1) * BH_;
        A1f = p.h0f + ((t + 1) & 1) * BH_;
        hout = p.h0b + (t & 1) * BH_;
        houtf = p.h0f + (t & 1) * BH_;
        Wi = p.Wi0; Wh = p.Wh0; bi = p.bi0; bh = p.bh0;
    } else if (cell == 1) {
        A0 = p.h0b + (t & 1) * BH_; ld0 = H_; K0 = H_;
        A1 = p.h1b + ((t + 1) & 1) * BH_;
        A1f = p.h1f + ((t + 1) & 1) * BH_;
        hout = p.h1b + (t & 1) * BH_;
        houtf = p.h1f + (t & 1) * BH_;
        Wi = p.Wi1; Wh = p.Wh1; bi = p.bi1; bh = p.bh1;
    } else {
        A0 = p.h1b + (t & 1) * BH_; ld0 = H_; K0 = H_;
        A1 = p.h2all + (size_t)t * BH_;
        A1f = p.h2f + ((t + 1) & 1) * BH_;
        hout = p.h2all + (size_t)(t + 1) * BH_;
        houtf = p.h2f + (t & 1) * BH_;
        Wi = p.Wi2; Wh = p.Wh2; bi = p.bi2; bh = p.bh2;
    }

    __shared__ u16 lds[2][4][64 * 32];   // [dbuf][A,Wr,Wz,Wn][64 rows x 32 k]

    int tid = threadIdx.x;
    int srow = tid >> 2;                          // staging row 0..63
    int ssoff = (((tid & 3) ^ (srow & 3)) << 3);  // swizzled k-chunk (elements)

    int wid = tid >> 6, lane = tid & 63;
    int wr = ((wid >> 1) << 5), wc = ((wid & 1) << 5);
    int fr = lane & 15, kc = lane >> 4;

    int aoff[2], boff[2];
#pragma unroll
    for (int m = 0; m < 2; ++m) {
        int rr = wr + 16 * m + fr;
        aoff[m] = rr * 32 + ((kc ^ (rr & 3)) << 3);
    }
#pragma unroll
    for (int n = 0; n < 2; ++n) {
        int cc = wc + 16 * n + fr;
        boff[n] = cc * 32 + ((kc ^ (cc & 3)) << 3);
    }

    f32x4 accR[2][2] = {{{0.f,0.f,0.f,0.f},{0.f,0.f,0.f,0.f}},{{0.f,0.f,0.f,0.f},{0.f,0.f,0.f,0.f}}};
    f32x4 accZ[2][2] = {{{0.f,0.f,0.f,0.f},{0.f,0.f,0.f,0.f}},{{0.f,0.f,0.f,0.f},{0.f,0.f,0.f,0.f}}};
    f32x4 accI[2][2] = {{{0.f,0.f,0.f,0.f},{0.f,0.f,0.f,0.f}},{{0.f,0.f,0.f,0.f},{0.f,0.f,0.f,0.f}}};
    f32x4 accN[2][2] = {{{0.f,0.f,0.f,0.f},{0.f,0.f,0.f,0.f}},{{0.f,0.f,0.f,0.f},{0.f,0.f,0.f,0.f}}};

    const int n0 = K0 >> 5;
    const int nIt = n0 + (H_ >> 5);

    // prologue: stage iteration 0 (seg0, kk = 0)
    {
        const u16* Ag = A0 + (size_t)(b0 + srow) * ld0 + ssoff;
        const u16* Wg = Wi + (size_t)(j0 + srow) * K0 + ssoff;
        gl_lds16(Ag, &lds[0][0][tid << 3]);
        gl_lds16(Wg, &lds[0][1][tid << 3]);
        gl_lds16(Wg + (size_t)H_ * K0, &lds[0][2][tid << 3]);
        gl_lds16(Wg + (size_t)(2 * H_) * K0, &lds[0][3][tid << 3]);
    }
    __syncthreads();

    for (int it = 0; it < nIt; ++it) {
        int cur = it & 1;
        int nx = it + 1;
        if (nx < nIt) {
            u16* dA = &lds[cur ^ 1][0][tid << 3];
            u16* dR = &lds[cur ^ 1][1][tid << 3];
            u16* dZ = &lds[cur ^ 1][2][tid << 3];
            u16* dN = &lds[cur ^ 1][3][tid << 3];
            if (nx < n0) {
                int kk = nx << 5;
                const u16* Ag = A0 + (size_t)(b0 + srow) * ld0 + kk + ssoff;
                const u16* Wg = Wi + (size_t)(j0 + srow) * K0 + kk + ssoff;
                gl_lds16(Ag, dA);
                gl_lds16(Wg, dR);
                gl_lds16(Wg + (size_t)H_ * K0, dZ);
                gl_lds16(Wg + (size_t)(2 * H_) * K0, dN);
            } else {
                int kk = (nx - n0) << 5;
                const u16* Ag = A1 + (size_t)(b0 + srow) * H_ + kk + ssoff;
                const u16* Wg = Wh + (size_t)(j0 + srow) * H_ + kk + ssoff;
                gl_lds16(Ag, dA);
                gl_lds16(Wg, dR);
                gl_lds16(Wg + (size_t)H_ * H_, dZ);
                gl_lds16(Wg + (size_t)(2 * H_) * H_, dN);
            }
        }
        bf16x8 a0 = *(const bf16x8*)&lds[cur][0][aoff[0]];
        bf16x8 a1 = *(const bf16x8*)&lds[cur][0][aoff[1]];
        bf16x8 r0 = *(const bf16x8*)&lds[cur][1][boff[0]];
        bf16x8 r1 = *(const bf16x8*)&lds[cur][1][boff[1]];
        bf16x8 z0 = *(const bf16x8*)&lds[cur][2][boff[0]];
        bf16x8 z1 = *(const bf16x8*)&lds[cur][2][boff[1]];
        bf16x8 q0 = *(const bf16x8*)&lds[cur][3][boff[0]];
        bf16x8 q1 = *(const bf16x8*)&lds[cur][3][boff[1]];

        accR[0][0] = MFMA16(a0, r0, accR[0][0]);
        accR[0][1] = MFMA16(a0, r1, accR[0][1]);
        accR[1][0] = MFMA16(a1, r0, accR[1][0]);
        accR[1][1] = MFMA16(a1, r1, accR[1][1]);
        accZ[0][0] = MFMA16(a0, z0, accZ[0][0]);
        accZ[0][1] = MFMA16(a0, z1, accZ[0][1]);
        accZ[1][0] = MFMA16(a1, z0, accZ[1][0]);
        accZ[1][1] = MFMA16(a1, z1, accZ[1][1]);
        if (it < n0) {  // x-segment -> i_n
            accI[0][0] = MFMA16(a0, q0, accI[0][0]);
            accI[0][1] = MFMA16(a0, q1, accI[0][1]);
            accI[1][0] = MFMA16(a1, q0, accI[1][0]);
            accI[1][1] = MFMA16(a1, q1, accI[1][1]);
        } else {        // h-segment -> h_n
            accN[0][0] = MFMA16(a0, q0, accN[0][0]);
            accN[0][1] = MFMA16(a0, q1, accN[0][1]);
            accN[1][0] = MFMA16(a1, q0, accN[1][0]);
            accN[1][1] = MFMA16(a1, q1, accN[1][1]);
        }
        __syncthreads();
    }

    // epilogue: gates + state update.  C/D layout: col=lane&15, row=(lane>>4)*4+i
#pragma unroll
    for (int m = 0; m < 2; ++m)
#pragma unroll
        for (int n = 0; n < 2; ++n) {
            int j = j0 + wc + 16 * n + fr;
            float b_r = bi[j] + bh[j];
            float b_z = bi[H_ + j] + bh[H_ + j];
            float b_i = bi[2 * H_ + j];
            float b_h = bh[2 * H_ + j];
#pragma unroll
            for (int i = 0; i < 4; ++i) {
                int brow = b0 + wr + 16 * m + kc * 4 + i;
                float rv = 1.f / (1.f + __expf(-(accR[m][n][i] + b_r)));
                float zv = 1.f / (1.f + __expf(-(accZ[m][n][i] + b_z)));
                float nv = tanhf(accI[m][n][i] + b_i + rv * (accN[m][n][i] + b_h));
                float hp = A1f[(size_t)brow * H_ + j];
                float hn = (1.f - zv) * nv + zv * hp;
                hout[(size_t)brow * H_ + j] = f2b(hn);
                houtf[(size_t)brow * H_ + j] = hn;
            }
        }
}

// ---------------- per-step linear head ----------------

__global__ __launch_bounds__(256) void k_linear(const u16* __restrict__ h2all,
                                                const u16* __restrict__ wT,
                                                const float* __restrict__ lb,
                                                float* __restrict__ out) {
    int bid = blockIdx.x;
    int t = bid >> 5;                 // 32 tiles per t
    int tile = bid & 31;
    int b0 = (tile >> 3) << 6;        // 4 b-tiles
    int o0 = (tile & 7) << 6;         // 8 o-tiles
    const u16* A = h2all + (size_t)(t + 1) * BH_;
    const u16* W = wT + (size_t)t * (O_ * H_);

    __shared__ u16 lds[2][2][64 * 32];
    int tid = threadIdx.x;
    int srow = tid >> 2;
    int ssoff = (((tid & 3) ^ (srow & 3)) << 3);
    int wid = tid >> 6, lane = tid & 63;
    int wr = ((wid >> 1) << 5), wc = ((wid & 1) << 5);
    int fr = lane & 15, kc = lane >> 4;
    int aoff[2], boff[2];
#pragma unroll
    for (int m = 0; m < 2; ++m) {
        int rr = wr + 16 * m + fr;
        aoff[m] = rr * 32 + ((kc ^ (rr & 3)) << 3);
    }
#pragma unroll
    for (int n = 0; n < 2; ++n) {
        int cc = wc + 16 * n + fr;
        boff[n] = cc * 32 + ((kc ^ (cc & 3)) << 3);
    }
    f32x4 acc[2][2] = {{{0.f,0.f,0.f,0.f},{0.f,0.f,0.f,0.f}},{{0.f,0.f,0.f,0.f},{0.f,0.f,0.f,0.f}}};

    gl_lds16(A + (size_t)(b0 + srow) * H_ + ssoff, &lds[0][0][tid << 3]);
    gl_lds16(W + (size_t)(o0 + srow) * H_ + ssoff, &lds[0][1][tid << 3]);
    __syncthreads();
    for (int it = 0; it < 32; ++it) {
        int cur = it & 1;
        if (it + 1 < 32) {
            int kk = (it + 1) << 5;
            gl_lds16(A + (size_t)(b0 + srow) * H_ + kk + ssoff, &lds[cur ^ 1][0][tid << 3]);
            gl_lds16(W + (size_t)(o0 + srow) * H_ + kk + ssoff, &lds[cur ^ 1][1][tid << 3]);
        }
        bf16x8 a0 = *(const bf16x8*)&lds[cur][0][aoff[0]];
        bf16x8 a1 = *(const bf16x8*)&lds[cur][0][aoff[1]];
        bf16x8 w0 = *(const bf16x8*)&lds[cur][1][boff[0]];
        bf16x8 w1 = *(const bf16x8*)&lds[cur][1][boff[1]];
        acc[0][0] = MFMA16(a0, w0, acc[0][0]);
        acc[0][1] = MFMA16(a0, w1, acc[0][1]);
        acc[1][0] = MFMA16(a1, w0, acc[1][0]);
        acc[1][1] = MFMA16(a1, w1, acc[1][1]);
        __syncthreads();
    }
#pragma unroll
    for (int m = 0; m < 2; ++m)
#pragma unroll
        for (int n = 0; n < 2; ++n) {
            int o = o0 + wc + 16 * n + fr;
            float bb = lb[t * O_ + o];
#pragma unroll
            for (int i = 0; i < 4; ++i) {
                int b = b0 + wr + 16 * m + kc * 4 + i;
                out[((size_t)b * S_ + t) * O_ + o] = acc[m][n][i] + bb;
            }
        }
}

// ---------------- final hidden-state outputs ----------------

__global__ void k_finals(const float* __restrict__ h0f, const float* __restrict__ h1f,
                         const float* __restrict__ h2f, float* __restrict__ out) {
    int i = blockIdx.x * blockDim.x + threadIdx.x;     // 3*BH_
    int c = i / BH_, r = i - c * BH_;
    // t=63 -> slot 63&1 = 1
    const float* s = (c == 0) ? (h0f + BH_) : (c == 1) ? (h1f + BH_) : (h2f + BH_);
    out[(size_t)B_ * S_ * O_ + (size_t)c * BH_ + r] = s[r];
}

// ---------------- launch ----------------

extern "C" void kernel_launch(void* const* d_in, const int* in_sizes, int n_in,
                              void* d_out, int out_size, void* d_ws, size_t ws_size,
                              hipStream_t stream) {
    (void)in_sizes; (void)n_in; (void)out_size; (void)ws_size;
    const float* x   = (const float*)d_in[0];
    const float* wi0 = (const float*)d_in[1];
    const float* wh0 = (const float*)d_in[2];
    const float* bi0 = (const float*)d_in[3];
    const float* bh0 = (const float*)d_in[4];
    const float* wi1 = (const float*)d_in[5];
    const float* wh1 = (const float*)d_in[6];
    const float* bi1 = (const float*)d_in[7];
    const float* bh1 = (const float*)d_in[8];
    const float* wi2 = (const float*)d_in[9];
    const float* wh2 = (const float*)d_in[10];
    const float* bi2 = (const float*)d_in[11];
    const float* bh2 = (const float*)d_in[12];
    const float* lw  = (const float*)d_in[13];
    const float* lb  = (const float*)d_in[14];

    char* base = (char*)d_ws;
    size_t off = 0;
    auto alloc = [&](size_t bytes) {
        char* p = base + off;
        off = (off + bytes + 255) & ~(size_t)255;
        return p;
    };
    u16* Xb  = (u16*)alloc((size_t)B_ * S_ * D_ * 2);
    u16* Wi0 = (u16*)alloc((size_t)G_ * D_ * 2);
    u16* Wh0 = (u16*)alloc((size_t)G_ * H_ * 2);
    u16* Wi1 = (u16*)alloc((size_t)G_ * H_ * 2);
    u16* Wh1 = (u16*)alloc((size_t)G_ * H_ * 2);
    u16* Wi2 = (u16*)alloc((size_t)G_ * H_ * 2);
    u16* Wh2 = (u16*)alloc((size_t)G_ * H_ * 2);
    u16* h0b = (u16*)alloc((size_t)2 * BH_ * 2);
    u16* h1b = (u16*)alloc((size_t)2 * BH_ * 2);
    u16* h2a = (u16*)alloc((size_t)(S_ + 1) * BH_ * 2);
    float* h0f = (float*)alloc((size_t)2 * BH_ * 4);
    float* h1f = (float*)alloc((size_t)2 * BH_ * 4);
    float* h2f = (float*)alloc((size_t)2 * BH_ * 4);
    u16* WLt = (u16*)alloc((size_t)S_ * O_ * H_ * 2);

    k_conv<<<2048, 256, 0, stream>>>(x,   Xb,  B_ * S_ * D_);
    k_conv<<<2048, 256, 0, stream>>>(wi0, Wi0, G_ * D_);
    k_conv<<<2048, 256, 0, stream>>>(wh0, Wh0, G_ * H_);
    k_conv<<<2048, 256, 0, stream>>>(wi1, Wi1, G_ * H_);
    k_conv<<<2048, 256, 0, stream>>>(wh1, Wh1, G_ * H_);
    k_conv<<<2048, 256, 0, stream>>>(wi2, Wi2, G_ * H_);
    k_conv<<<2048, 256, 0, stream>>>(wh2, Wh2, G_ * H_);
    k_twl<<<S_ * 512, 256, 0, stream>>>(lw, WLt);
    hipMemsetAsync(h0b, 0, (size_t)2 * BH_ * 2, stream);
    hipMemsetAsync(h1b, 0, (size_t)2 * BH_ * 2, stream);
    hipMemsetAsync(h2a, 0, (size_t)BH_ * 2, stream);          // slot 0 = t=-1
    hipMemsetAsync(h0f, 0, (size_t)2 * BH_ * 4, stream);
    hipMemsetAsync(h1f, 0, (size_t)2 * BH_ * 4, stream);
    hipMemsetAsync(h2f, 0, (size_t)2 * BH_ * 4, stream);

    PhaseArgs pa;
    pa.Xb = Xb;
    pa.Wi0 = Wi0; pa.Wh0 = Wh0; pa.Wi1 = Wi1; pa.Wh1 = Wh1; pa.Wi2 = Wi2; pa.Wh2 = Wh2;
    pa.bi0 = bi0; pa.bh0 = bh0; pa.bi1 = bi1; pa.bh1 = bh1; pa.bi2 = bi2; pa.bh2 = bh2;
    pa.h0b = h0b; pa.h1b = h1b; pa.h2all = h2a;
    pa.h0f = h0f; pa.h1f = h1f; pa.h2f = h2f;

    for (int k = 0; k < S_ + 2; ++k)
        k_phase<<<192, 256, 0, stream>>>(pa, k);

    k_linear<<<S_ * 32, 256, 0, stream>>>(h2a, WLt, lb, (float*)d_out);
    k_finals<<<(3 * BH_) / 256, 256, 0, stream>>>(h0f, h1f, h2f, (float*)d_out);
}